// Round 11
// baseline (1258.168 us; speedup 1.0000x reference)
//
#include <hip/hip_runtime.h>
#include <hip/hip_bf16.h>
#include <math.h>

#define B_   16
#define S_   512
#define E_   1024
#define H_   16
#define D_   64
#define NL_  6
#define OUT_ 10
#define M_   (B_*S_)

typedef short short8 __attribute__((ext_vector_type(8)));
typedef float f32x4 __attribute__((ext_vector_type(4)));
typedef int   int4v __attribute__((ext_vector_type(4)));
typedef unsigned short ushort4v __attribute__((ext_vector_type(4)));

typedef const __attribute__((address_space(1))) unsigned int* gas1_t;
typedef __attribute__((address_space(3))) unsigned int* las3_t;
#define GLD16(g,l) __builtin_amdgcn_global_load_lds((gas1_t)(g), (las3_t)(l), 16, 0, 0)

static __device__ __forceinline__ unsigned short f2bf(float f){
  union { float f; unsigned int i; } v; v.f = f;
  unsigned int r = v.i + 0x7fffu + ((v.i >> 16) & 1u);
  return (unsigned short)(r >> 16);
}
static __device__ __forceinline__ f32x4 mfma16(short8 a, short8 b, f32x4 c){
  return __builtin_amdgcn_mfma_f32_16x16x32_bf16(a, b, c, 0, 0, 0);
}

// ---------------- code writer (f32 output) ----------------
__global__ __launch_bounds__(192)
void code_k(float* __restrict__ out, float code)
{
  int t = threadIdx.x;
  if (t < B_*OUT_) out[t] = code;
}

// ---------------- weight transpose + f32->bf16: wT[n][k] = bf16(w[k][n]) ----------------
__global__ __launch_bounds__(256)
void transpose_k(const float* __restrict__ w0, const float* __restrict__ w1,
                 const float* __restrict__ w2, const float* __restrict__ w3,
                 unsigned short* __restrict__ wT)
{
  const float* w = blockIdx.z==0 ? w0 : blockIdx.z==1 ? w1 : blockIdx.z==2 ? w2 : w3;
  unsigned short* o = wT + (size_t)blockIdx.z * E_ * E_;
  __shared__ unsigned short tl[64][65];
  int n0 = blockIdx.x*64, k0 = blockIdx.y*64;
  int tx = threadIdx.x, ty = threadIdx.y;
  #pragma unroll
  for (int i = 0; i < 16; ++i)
    tl[ty + 4*i][tx] = f2bf(w[(size_t)(k0 + ty + 4*i)*E_ + n0 + tx]);
  __syncthreads();
  #pragma unroll
  for (int i = 0; i < 16; ++i)
    o[(size_t)(n0 + ty + 4*i)*E_ + k0 + tx] = tl[tx][ty + 4*i];
}

// ---------------- embedding + positional: x = 2*emb[tok] + pe[b,e] (batch-indexed, faithful) ----------------
__global__ __launch_bounds__(256)
void embed_k(const int* __restrict__ tok, const float* __restrict__ emb,
             float* __restrict__ x, unsigned short* __restrict__ xb)
{
  int row = blockIdx.x;            // b*512+s
  int b = row >> 9;
  int tk = tok[row];
  tk = tk < 0 ? 0 : (tk > 15 ? 15 : tk);
  int e0 = threadIdx.x * 4;
  const float c0 = -9.210340371976184f / (float)E_;   // -ln(10000)/E
  f32x4 ev = *(const f32x4*)&emb[(size_t)tk * E_ + e0];
  f32x4 vv; ushort4v bb;
  #pragma unroll
  for (int i = 0; i < 4; ++i) {
    int e = e0 + i;
    float dv = expf((float)(e & ~1) * c0);
    float arg = (float)b * dv;
    float pe = (e & 1) ? cosf(arg) : sinf(arg);
    float v = 2.0f * ev[i] + pe;
    vv[i] = v; bb[i] = f2bf(v);
  }
  *(f32x4*)&x[(size_t)row*E_ + e0] = vv;
  *(ushort4v*)&xb[(size_t)row*E_ + e0] = bb;
}

// ---------------- 128x128 bf16 MFMA GEMM, BT = [N][K], T2 XOR-swizzled LDS ----------------
// MODE 0: fused QKV (grid.y = 24). Q,K written [B,H,S,D]; V (wsel==2) written TRANSPOSED [B,H,D,S].
// MODE 1: FC (grid.y = 8), writes f32 [M][N]
template<int MODE>
__global__ __launch_bounds__(256)
void gemm_bt_k(const unsigned short* __restrict__ A,
               const unsigned short* __restrict__ BT,
               const float* __restrict__ bias0, const float* __restrict__ bias1,
               const float* __restrict__ bias2,
               unsigned short* __restrict__ outq, float* __restrict__ outf)
{
  __shared__ alignas(16) unsigned short SM[17408];   // Al(8192) + Bl(8192); Ct(17408) overlay
  unsigned short* Al = SM;
  unsigned short* Bl = SM + 8192;
  int mt = blockIdx.x;
  int nyt = blockIdx.y;
  int wsel = (MODE == 0) ? (nyt >> 3) : 0;
  int nt   = (MODE == 0) ? (nyt & 7) : nyt;
  const unsigned short* Bp = BT + (size_t)wsel * E_ * E_ + (size_t)nt * 128 * E_;
  const float* bias = (MODE == 0) ? (wsel == 0 ? bias0 : (wsel == 1 ? bias1 : bias2)) : bias0;
  int tid = threadIdx.x;
  int lane = tid & 63, wid = tid >> 6;
  int wr = wid >> 1, wc = wid & 1;
  int m0 = mt * 128;
  int lr = lane & 15, lk = lane >> 4;
  int lx = lr & 7;                       // row&7 for the read-side swizzle
  int c8 = tid & 7;
  int rbase = tid >> 3;                  // r = j*32 + rbase
  int c8s = c8 ^ (rbase & 7);
  f32x4 acc[4][4] = {};
  for (int kt = 0; kt < E_/64; ++kt) {
    #pragma unroll
    for (int j = 0; j < 4; ++j) {
      int r = j*32 + rbase;
      int idx = j*256 + tid;
      GLD16(A + (size_t)(m0 + r)*E_ + kt*64 + c8s*8, &Al[idx*8]);
      GLD16(Bp + (size_t)r*E_ + kt*64 + c8s*8, &Bl[idx*8]);
    }
    __syncthreads();
    #pragma unroll
    for (int kk = 0; kk < 2; ++kk) {
      int sA = ((kk*4 + lk) ^ lx) * 8;   // swizzled 16B-chunk within the 128B row
      short8 af[4], bfr[4];
      #pragma unroll
      for (int mi = 0; mi < 4; ++mi)
        af[mi] = *(const short8*)&Al[(wr*64 + mi*16 + lr)*64 + sA];
      #pragma unroll
      for (int ni = 0; ni < 4; ++ni)
        bfr[ni] = *(const short8*)&Bl[(wc*64 + ni*16 + lr)*64 + sA];
      #pragma unroll
      for (int mi = 0; mi < 4; ++mi)
        #pragma unroll
        for (int ni = 0; ni < 4; ++ni)
          acc[mi][ni] = mfma16(af[mi], bfr[ni], acc[mi][ni]);
    }
    __syncthreads();
  }
  if (MODE == 0) {
    if (wsel == 2) {
      // V: build TRANSPOSED tile Ct[d_local][m_local] (pad 136), write VT[B,H,D,S]
      unsigned short* Ct = SM;
      #pragma unroll
      for (int ni = 0; ni < 4; ++ni) {
        int nl = wc*64 + ni*16 + lr;
        float bv = bias[nt*128 + nl];
        #pragma unroll
        for (int mi = 0; mi < 4; ++mi)
          #pragma unroll
          for (int j = 0; j < 4; ++j)
            Ct[nl*136 + wr*64 + mi*16 + lk*4 + j] = f2bf(acc[mi][ni][j] + bv);
      }
      __syncthreads();
      int dl = tid >> 1, half = tid & 1;
      int h = nt*2 + (dl >> 6), d = dl & 63;
      int bb = m0 >> 9, s0 = (m0 & 511) + half*64;
      unsigned short* gp = outq + (size_t)2*M_*E_ +
                           (((size_t)(bb*H_ + h)*D_ + d)*S_ + s0);
      #pragma unroll
      for (int c = 0; c < 8; ++c)
        *(int4v*)(gp + c*8) = *(const int4v*)&Ct[dl*136 + half*64 + c*8];
    } else {
      // Q,K: stage C tile, coalesced [B,H,S,D] stores
      unsigned short* Cl = SM;
      #pragma unroll
      for (int ni = 0; ni < 4; ++ni) {
        int n = nt*128 + wc*64 + ni*16 + lr;
        float bv = bias[n];
        #pragma unroll
        for (int mi = 0; mi < 4; ++mi)
          #pragma unroll
          for (int j = 0; j < 4; ++j)
            Cl[(wr*64 + mi*16 + lk*4 + j)*128 + wc*64 + ni*16 + lr] =
              f2bf(acc[mi][ni][j] + bv);
      }
      __syncthreads();
      int r = tid >> 1, half = tid & 1;
      int m = m0 + r;
      int bb = m >> 9, s = m & 511;
      int h = nt*2 + half;
      unsigned short* gp = outq + (size_t)wsel*M_*E_ + (((size_t)(bb*H_ + h)*S_ + s)*D_);
      #pragma unroll
      for (int c = 0; c < 8; ++c)
        *(int4v*)(gp + c*8) = *(const int4v*)&Cl[r*128 + half*64 + c*8];
    }
  } else {
    #pragma unroll
    for (int ni = 0; ni < 4; ++ni) {
      int n = nt*128 + wc*64 + ni*16 + lr;
      float bv = bias[n];
      #pragma unroll
      for (int mi = 0; mi < 4; ++mi) {
        #pragma unroll
        for (int j = 0; j < 4; ++j) {
          int m = m0 + wr*64 + mi*16 + lk*4 + j;
          outf[(size_t)m*E_ + n] = acc[mi][ni][j] + bv;
        }
      }
    }
  }
}

// ---------------- flash attention: grid (qc=4, bh=256), 8 waves ----------------
// K staged in LDS; V read directly from VT[B,H,D,S] (L2-resident, contiguous 16B frags)
__global__ __launch_bounds__(512)
void attn_k(const unsigned short* __restrict__ Q, const unsigned short* __restrict__ K,
            const unsigned short* __restrict__ VT, float* __restrict__ O)
{
  __shared__ alignas(16) unsigned short Kl[128*72];
  __shared__ alignas(16) unsigned short Pl[8][16*40];
  int bh = blockIdx.y, qc = blockIdx.x;
  int tid = threadIdx.x, lane = tid & 63, wid = tid >> 6;
  int lr = lane & 15, lk = lane >> 4;
  int q0 = qc*128 + wid*16;
  const unsigned short* Qb = Q + (size_t)bh * S_ * D_;
  const unsigned short* Kb = K + (size_t)bh * S_ * D_;
  const unsigned short* VTb = VT + (size_t)bh * S_ * D_;   // [d][s]
  short8 qf[2];
  #pragma unroll
  for (int kk = 0; kk < 2; ++kk)
    qf[kk] = *(const short8*)(Qb + (size_t)(q0 + lr)*D_ + kk*32 + lk*8);
  f32x4 oacc[4] = {};
  float mrow[4] = {-1e30f,-1e30f,-1e30f,-1e30f};
  float lsum[4] = {0.f,0.f,0.f,0.f};
  unsigned short* Pw = Pl[wid];
  for (int kt = 0; kt < 4; ++kt) {
    {
      int idx = tid;                     // 512 threads, 2 chunks each
      #pragma unroll
      for (int j = 0; j < 2; ++j, idx += 512) {
        int r = idx >> 3, c8 = idx & 7;
        int4v kv = *(const int4v*)(Kb + (size_t)(kt*128 + r)*D_ + c8*8);
        *(int4v*)&Kl[r*72 + c8*8] = kv;
      }
    }
    __syncthreads();
    f32x4 sc[8];
    #pragma unroll
    for (int t = 0; t < 8; ++t) {
      short8 kf0 = *(const short8*)&Kl[(t*16 + lr)*72 + lk*8];
      short8 kf1 = *(const short8*)&Kl[(t*16 + lr)*72 + 32 + lk*8];
      f32x4 s = {};
      s = mfma16(qf[0], kf0, s);
      s = mfma16(qf[1], kf1, s);
      sc[t] = s * 0.125f;                      // 1/sqrt(64)
    }
    #pragma unroll
    for (int j = 0; j < 4; ++j) {
      float mx = -1e30f;
      #pragma unroll
      for (int t = 0; t < 8; ++t) mx = fmaxf(mx, sc[t][j]);
      #pragma unroll
      for (int m = 1; m < 16; m <<= 1) mx = fmaxf(mx, __shfl_xor(mx, m));
      float mn = fmaxf(mrow[j], mx);
      float alpha = __expf(mrow[j] - mn);
      mrow[j] = mn;
      float rs = 0.f;
      #pragma unroll
      for (int t = 0; t < 8; ++t) { float p = __expf(sc[t][j] - mn); sc[t][j] = p; rs += p; }
      #pragma unroll
      for (int m = 1; m < 16; m <<= 1) rs += __shfl_xor(rs, m);
      lsum[j] = lsum[j]*alpha + rs;
      #pragma unroll
      for (int dt = 0; dt < 4; ++dt) oacc[dt][j] *= alpha;
    }
    #pragma unroll
    for (int c = 0; c < 4; ++c) {
      #pragma unroll
      for (int j = 0; j < 4; ++j) {
        Pw[(lk*4 + j)*40 + lr]      = f2bf(sc[2*c  ][j]);
        Pw[(lk*4 + j)*40 + 16 + lr] = f2bf(sc[2*c+1][j]);
      }
      // drain this wave's ds_writes so the cross-lane ds_read below sees them
      asm volatile("s_waitcnt lgkmcnt(0)" ::: "memory");
      short8 pf = *(const short8*)&Pw[lr*40 + lk*8];
      #pragma unroll
      for (int dt = 0; dt < 4; ++dt) {
        short8 vf = *(const short8*)(VTb + (size_t)(dt*16 + lr)*S_ + kt*128 + c*32 + lk*8);
        oacc[dt] = mfma16(pf, vf, oacc[dt]);
      }
    }
    __syncthreads();
  }
  #pragma unroll
  for (int dt = 0; dt < 4; ++dt) {
    #pragma unroll
    for (int j = 0; j < 4; ++j) {
      float v = oacc[dt][j] / lsum[j];
      O[(size_t)bh*S_*D_ + (size_t)(q0 + lk*4 + j)*D_ + dt*16 + lr] = v;
    }
  }
}

// ---------------- residual + layernorm (f32 stream + bf16 copy) ----------------
template<bool PERM>
__global__ __launch_bounds__(256)
void ln_k(const float* __restrict__ g, float* __restrict__ x, unsigned short* __restrict__ xb,
          const float* __restrict__ gamma, const float* __restrict__ beta)
{
  int row = blockIdx.x;
  int tid = threadIdx.x;
  int e0 = tid * 4;
  f32x4 gv;
  if (PERM) {
    int b = row >> 9, s = row & 511;
    int h = e0 >> 6, d = e0 & 63;
    gv = *(const f32x4*)&g[(((size_t)(b*H_ + h)*S_) + s)*D_ + d];
  } else {
    gv = *(const f32x4*)&g[(size_t)row*E_ + e0];
  }
  f32x4 xv = *(const f32x4*)&x[(size_t)row*E_ + e0];
  f32x4 v = gv + xv;
  float sum = v[0]+v[1]+v[2]+v[3];
  float sq  = v[0]*v[0]+v[1]*v[1]+v[2]*v[2]+v[3]*v[3];
  #pragma unroll
  for (int m = 1; m < 64; m <<= 1) { sum += __shfl_xor(sum, m); sq += __shfl_xor(sq, m); }
  __shared__ float red[2][4];
  int lane = tid & 63, wid = tid >> 6;
  if (lane == 0) { red[0][wid] = sum; red[1][wid] = sq; }
  __syncthreads();
  float ts = red[0][0]+red[0][1]+red[0][2]+red[0][3];
  float tq = red[1][0]+red[1][1]+red[1][2]+red[1][3];
  float mu = ts * (1.0f/E_);
  float var = tq * (1.0f/E_) - mu*mu;
  float rsq = rsqrtf(var + 1e-5f);
  f32x4 y; ushort4v yb;
  #pragma unroll
  for (int i = 0; i < 4; ++i) {
    float t = (v[i]-mu)*rsq*gamma[e0+i] + beta[e0+i];
    y[i] = t; yb[i] = f2bf(t);
  }
  *(f32x4*)&x[(size_t)row*E_ + e0] = y;
  *(ushort4v*)&xb[(size_t)row*E_ + e0] = yb;
}

// ---------------- output head (all f32, exact) ----------------
__global__ __launch_bounds__(256)
void outp_k(const float* __restrict__ x, const float* __restrict__ wout,
            float* __restrict__ part)
{
  int b = blockIdx.y;
  int chunk = blockIdx.x;
  int tid = threadIdx.x;
  float acc[OUT_] = {};
  const float* xr = x + (size_t)b * S_ * E_;
  for (int j = 0; j < 32; ++j) {
    int k = chunk*8192 + j*256 + tid;
    float xv = xr[k];
    const float* wr = wout + (size_t)k * OUT_;
    #pragma unroll
    for (int o = 0; o < OUT_; ++o) acc[o] += xv * wr[o];
  }
  #pragma unroll
  for (int o = 0; o < OUT_; ++o)
    #pragma unroll
    for (int m = 1; m < 64; m <<= 1) acc[o] += __shfl_xor(acc[o], m);
  __shared__ float red[4][OUT_];
  int lane = tid & 63, wid = tid >> 6;
  if (lane == 0) {
    #pragma unroll
    for (int o = 0; o < OUT_; ++o) red[wid][o] = acc[o];
  }
  __syncthreads();
  if (tid < OUT_) {
    float s = red[0][tid] + red[1][tid] + red[2][tid] + red[3][tid];
    part[((size_t)chunk*B_ + b)*OUT_ + tid] = s;
  }
}

__global__ __launch_bounds__(192)
void outred_k(const float* __restrict__ part, const float* __restrict__ bout,
              float* __restrict__ out)
{
  int t = threadIdx.x;
  if (t < B_*OUT_) {
    int b = t / OUT_, o = t % OUT_;
    float s = 0.f;
    for (int c = 0; c < 64; ++c) s += part[((size_t)c*B_ + b)*OUT_ + o];
    s += bout[o];
    out[t] = s;
  }
}

extern "C" void kernel_launch(void* const* d_in, const int* in_sizes, int n_in,
                              void* d_out, int out_size, void* d_ws, size_t ws_size,
                              hipStream_t stream)
{
  (void)out_size;
  float* outb = (float*)d_out;

  static const int expect[14] = {8192, 16384, 1048576, 1024, 1048576, 1024,
                                 1048576, 1024, 1048576, 1024, 1024, 1024,
                                 5242880, 10};
  if (n_in != 14) { code_k<<<dim3(1), dim3(192), 0, stream>>>(outb, 9000.0f); return; }
  for (int i = 0; i < 14; ++i)
    if (in_sizes[i] != expect[i]) {
      code_k<<<dim3(1), dim3(192), 0, stream>>>(outb, 5000.0f + 100.0f*i); return;
    }

  const int* tok = (const int*)d_in[0];
  const float* emb  = (const float*)d_in[1];
  const float* wq   = (const float*)d_in[2];
  const float* bq   = (const float*)d_in[3];
  const float* wk   = (const float*)d_in[4];
  const float* bk   = (const float*)d_in[5];
  const float* wv   = (const float*)d_in[6];
  const float* bv   = (const float*)d_in[7];
  const float* wfc  = (const float*)d_in[8];
  const float* bfc  = (const float*)d_in[9];
  const float* gam  = (const float*)d_in[10];
  const float* bet  = (const float*)d_in[11];
  const float* wout = (const float*)d_in[12];
  const float* bout = (const float*)d_in[13];

  char* ws = (char*)d_ws;
  size_t off = 0;
  unsigned short* wT = (unsigned short*)(ws + off); off += (size_t)4*E_*E_*2;
  float* x  = (float*)(ws + off);            off += (size_t)M_*E_*4;
  unsigned short* xb = (unsigned short*)(ws + off); off += (size_t)M_*E_*2;
  unsigned short* qkvb = (unsigned short*)(ws + off); off += (size_t)3*M_*E_*2;
  float* g  = (float*)(ws + off);            off += (size_t)M_*E_*4;
  float* part = (float*)(ws + off);          off += (size_t)64*B_*OUT_*4;
  if (off > ws_size) { code_k<<<dim3(1), dim3(192), 0, stream>>>(outb, 9500.0f); return; }

  transpose_k<<<dim3(16,16,4), dim3(64,4), 0, stream>>>(wq, wk, wv, wfc, wT);
  embed_k<<<dim3(M_), dim3(256), 0, stream>>>(tok, emb, x, xb);
  unsigned short* qb = qkvb;
  unsigned short* kb = qkvb + (size_t)M_*E_;
  unsigned short* vb = qkvb + (size_t)2*M_*E_;   // holds VT [B,H,D,S]
  for (int l = 0; l < NL_; ++l) {
    gemm_bt_k<0><<<dim3(64,24), dim3(256), 0, stream>>>(xb, wT, bq, bk, bv, qkvb, nullptr);
    attn_k<<<dim3(4,256), dim3(512), 0, stream>>>(qb, kb, vb, g);
    ln_k<true><<<dim3(M_), dim3(256), 0, stream>>>(g, x, xb, gam, bet);
    gemm_bt_k<1><<<dim3(64,8), dim3(256), 0, stream>>>(xb, wT + (size_t)3*E_*E_, bfc, bfc, bfc, nullptr, g);
    ln_k<false><<<dim3(M_), dim3(256), 0, stream>>>(g, x, xb, gam, bet);
  }
  outp_k<<<dim3(64,B_), dim3(256), 0, stream>>>(x, wout, part);
  outred_k<<<dim3(1), dim3(192), 0, stream>>>(part, bout, outb);
}

// Round 12
// 1250.560 us; speedup vs baseline: 1.0061x; 1.0061x over previous
//
#include <hip/hip_runtime.h>
#include <hip/hip_bf16.h>
#include <math.h>

#define B_   16
#define S_   512
#define E_   1024
#define H_   16
#define D_   64
#define NL_  6
#define OUT_ 10
#define M_   (B_*S_)

typedef short short8 __attribute__((ext_vector_type(8)));
typedef float f32x4 __attribute__((ext_vector_type(4)));
typedef int   int4v __attribute__((ext_vector_type(4)));
typedef unsigned short ushort4v __attribute__((ext_vector_type(4)));

typedef const __attribute__((address_space(1))) unsigned int* gas1_t;
typedef __attribute__((address_space(3))) unsigned int* las3_t;
#define GLD16(g,l) __builtin_amdgcn_global_load_lds((gas1_t)(g), (las3_t)(l), 16, 0, 0)

static __device__ __forceinline__ float bf2f(unsigned short u){
  union { unsigned int i; float f; } v; v.i = ((unsigned int)u) << 16; return v.f;
}
static __device__ __forceinline__ unsigned short f2bf(float f){
  union { float f; unsigned int i; } v; v.f = f;
  unsigned int r = v.i + 0x7fffu + ((v.i >> 16) & 1u);
  return (unsigned short)(r >> 16);
}
static __device__ __forceinline__ f32x4 mfma16(short8 a, short8 b, f32x4 c){
  return __builtin_amdgcn_mfma_f32_16x16x32_bf16(a, b, c, 0, 0, 0);
}

// ---------------- code writer (f32 output) ----------------
__global__ __launch_bounds__(192)
void code_k(float* __restrict__ out, float code)
{
  int t = threadIdx.x;
  if (t < B_*OUT_) out[t] = code;
}

// ---------------- weight transpose + f32->bf16: wT[n][k] = bf16(w[k][n]) ----------------
__global__ __launch_bounds__(256)
void transpose_k(const float* __restrict__ w0, const float* __restrict__ w1,
                 const float* __restrict__ w2, const float* __restrict__ w3,
                 unsigned short* __restrict__ wT)
{
  const float* w = blockIdx.z==0 ? w0 : blockIdx.z==1 ? w1 : blockIdx.z==2 ? w2 : w3;
  unsigned short* o = wT + (size_t)blockIdx.z * E_ * E_;
  __shared__ unsigned short tl[64][65];
  int n0 = blockIdx.x*64, k0 = blockIdx.y*64;
  int tx = threadIdx.x, ty = threadIdx.y;
  #pragma unroll
  for (int i = 0; i < 16; ++i)
    tl[ty + 4*i][tx] = f2bf(w[(size_t)(k0 + ty + 4*i)*E_ + n0 + tx]);
  __syncthreads();
  #pragma unroll
  for (int i = 0; i < 16; ++i)
    o[(size_t)(n0 + ty + 4*i)*E_ + k0 + tx] = tl[tx][ty + 4*i];
}

// ---------------- embedding + positional: x = 2*emb[tok] + pe[b,e] (batch-indexed, faithful) ----------------
__global__ __launch_bounds__(256)
void embed_k(const int* __restrict__ tok, const float* __restrict__ emb,
             float* __restrict__ x, unsigned short* __restrict__ xb)
{
  int row = blockIdx.x;            // b*512+s
  int b = row >> 9;
  int tk = tok[row];
  tk = tk < 0 ? 0 : (tk > 15 ? 15 : tk);
  int e0 = threadIdx.x * 4;
  const float c0 = -9.210340371976184f / (float)E_;   // -ln(10000)/E
  f32x4 ev = *(const f32x4*)&emb[(size_t)tk * E_ + e0];
  f32x4 vv; ushort4v bb;
  #pragma unroll
  for (int i = 0; i < 4; ++i) {
    int e = e0 + i;
    float dv = expf((float)(e & ~1) * c0);
    float arg = (float)b * dv;
    float pe = (e & 1) ? cosf(arg) : sinf(arg);
    float v = 2.0f * ev[i] + pe;
    vv[i] = v; bb[i] = f2bf(v);
  }
  *(f32x4*)&x[(size_t)row*E_ + e0] = vv;
  *(ushort4v*)&xb[(size_t)row*E_ + e0] = bb;
}

// ---------------- 128x128 bf16 MFMA GEMM, BT = [N][K], T2 XOR-swizzled LDS ----------------
// MODE 0: QK (grid.y=16): wsel=nyt>>3 (0=Q,1=K), writes bf16 [B,H,S,D] at outq+wsel*M*E
// MODE 2: V  (grid.y=8):  writes TRANSPOSED bf16 [B,H,D,S] at outq
// MODE 1: FC (grid.y=8):  writes bf16 [M][E] at outq
template<int MODE>
__global__ __launch_bounds__(256)
void gemm_bt_k(const unsigned short* __restrict__ A,
               const unsigned short* __restrict__ BT,
               const float* __restrict__ biasA, const float* __restrict__ biasB,
               unsigned short* __restrict__ outq)
{
  __shared__ alignas(16) unsigned short SM[(MODE==2) ? 17408 : 16384];
  unsigned short* Al = SM;
  unsigned short* Bl = SM + 8192;
  int mt = blockIdx.x;
  int nyt = blockIdx.y;
  int wsel = (MODE == 0) ? (nyt >> 3) : 0;
  int nt   = (MODE == 0) ? (nyt & 7) : nyt;
  const unsigned short* Bp = BT + (size_t)wsel * E_ * E_ + (size_t)nt * 128 * E_;
  const float* bias = (MODE == 0) ? (wsel == 0 ? biasA : biasB) : biasA;
  int tid = threadIdx.x;
  int lane = tid & 63, wid = tid >> 6;
  int wr = wid >> 1, wc = wid & 1;
  int m0 = mt * 128;
  int lr = lane & 15, lk = lane >> 4;
  int lx = lr & 7;
  int c8 = tid & 7;
  int rbase = tid >> 3;                  // r = j*32 + rbase
  int c8s = c8 ^ (rbase & 7);
  f32x4 acc[4][4] = {};
  for (int kt = 0; kt < E_/64; ++kt) {
    #pragma unroll
    for (int j = 0; j < 4; ++j) {
      int r = j*32 + rbase;
      int idx = j*256 + tid;
      GLD16(A + (size_t)(m0 + r)*E_ + kt*64 + c8s*8, &Al[idx*8]);
      GLD16(Bp + (size_t)r*E_ + kt*64 + c8s*8, &Bl[idx*8]);
    }
    __syncthreads();
    #pragma unroll
    for (int kk = 0; kk < 2; ++kk) {
      int sA = ((kk*4 + lk) ^ lx) * 8;
      short8 af[4], bfr[4];
      #pragma unroll
      for (int mi = 0; mi < 4; ++mi)
        af[mi] = *(const short8*)&Al[(wr*64 + mi*16 + lr)*64 + sA];
      #pragma unroll
      for (int ni = 0; ni < 4; ++ni)
        bfr[ni] = *(const short8*)&Bl[(wc*64 + ni*16 + lr)*64 + sA];
      #pragma unroll
      for (int mi = 0; mi < 4; ++mi)
        #pragma unroll
        for (int ni = 0; ni < 4; ++ni)
          acc[mi][ni] = mfma16(af[mi], bfr[ni], acc[mi][ni]);
    }
    __syncthreads();
  }
  if (MODE == 2) {
    // V: transposed tile Ct[d_local][m_local] (pad 136), write VT[B,H,D,S]
    unsigned short* Ct = SM;
    #pragma unroll
    for (int ni = 0; ni < 4; ++ni) {
      int nl = wc*64 + ni*16 + lr;
      float bv = bias[nt*128 + nl];
      #pragma unroll
      for (int mi = 0; mi < 4; ++mi)
        #pragma unroll
        for (int j = 0; j < 4; ++j)
          Ct[nl*136 + wr*64 + mi*16 + lk*4 + j] = f2bf(acc[mi][ni][j] + bv);
    }
    __syncthreads();
    int dl = tid >> 1, half = tid & 1;
    int h = nt*2 + (dl >> 6), d = dl & 63;
    int bb = m0 >> 9, s0 = (m0 & 511) + half*64;
    unsigned short* gp = outq + (((size_t)(bb*H_ + h)*D_ + d)*S_ + s0);
    #pragma unroll
    for (int c = 0; c < 8; ++c)
      *(int4v*)(gp + c*8) = *(const int4v*)&Ct[dl*136 + half*64 + c*8];
  } else {
    // QK / FC: stage row-major tile, coalesced stores
    unsigned short* Cl = SM;
    #pragma unroll
    for (int ni = 0; ni < 4; ++ni) {
      int n = nt*128 + wc*64 + ni*16 + lr;
      float bv = bias[n];
      #pragma unroll
      for (int mi = 0; mi < 4; ++mi)
        #pragma unroll
        for (int j = 0; j < 4; ++j)
          Cl[(wr*64 + mi*16 + lk*4 + j)*128 + wc*64 + ni*16 + lr] =
            f2bf(acc[mi][ni][j] + bv);
    }
    __syncthreads();
    int r = tid >> 1, half = tid & 1;
    int m = m0 + r;
    unsigned short* gp;
    if (MODE == 0) {
      int bb = m >> 9, s = m & 511;
      int h = nt*2 + half;
      gp = outq + (size_t)wsel*M_*E_ + (((size_t)(bb*H_ + h)*S_ + s)*D_);
    } else {
      gp = outq + (size_t)m*E_ + nt*128 + half*64;
    }
    const unsigned short* sp = &Cl[r*128 + half*64];
    #pragma unroll
    for (int c = 0; c < 8; ++c)
      *(int4v*)(gp + c*8) = *(const int4v*)(sp + c*8);
  }
}

// ---------------- flash attention, no-max single-pass softmax ----------------
// grid (qc=4, bh=256), 8 waves. K staged via global_load_lds + swizzle; V read from VT[B,H,D,S].
// Output bf16 [B,H,S,D].
__global__ __launch_bounds__(512)
void attn_k(const unsigned short* __restrict__ Q, const unsigned short* __restrict__ K,
            const unsigned short* __restrict__ VT, unsigned short* __restrict__ O)
{
  __shared__ alignas(16) unsigned short Kl[128*64];
  __shared__ alignas(16) unsigned short Pl[8][16*40];
  int bh = blockIdx.y, qc = blockIdx.x;
  int tid = threadIdx.x, lane = tid & 63, wid = tid >> 6;
  int lr = lane & 15, lk = lane >> 4;
  int q0 = qc*128 + wid*16;
  const unsigned short* Qb = Q + (size_t)bh * S_ * D_;
  const unsigned short* Kb = K + (size_t)bh * S_ * D_;
  const unsigned short* VTb = VT + (size_t)bh * S_ * D_;   // [d][s]
  short8 qf[2];
  #pragma unroll
  for (int kk = 0; kk < 2; ++kk)
    qf[kk] = *(const short8*)(Qb + (size_t)(q0 + lr)*D_ + kk*32 + lk*8);
  f32x4 oacc[4] = {};
  float plsum[4] = {0.f,0.f,0.f,0.f};
  unsigned short* Pw = Pl[wid];
  // staging geometry: 1024 chunks of 16B; idx -> r=idx>>3, c8=idx&7, src chunk c8^(r&7)
  for (int kt = 0; kt < 4; ++kt) {
    #pragma unroll
    for (int j = 0; j < 2; ++j) {
      int idx = j*512 + tid;
      int r = idx >> 3, c8v = idx & 7;
      int c8s = c8v ^ (r & 7);
      GLD16(Kb + (size_t)(kt*128 + r)*D_ + c8s*8, &Kl[idx*8]);
    }
    __syncthreads();
    f32x4 sc[8];
    #pragma unroll
    for (int t = 0; t < 8; ++t) {
      short8 kf0 = *(const short8*)&Kl[(t*16 + lr)*64 + ((lk   ^ (lr&7)))*8];
      short8 kf1 = *(const short8*)&Kl[(t*16 + lr)*64 + (((4+lk) ^ (lr&7)))*8];
      f32x4 s = {};
      s = mfma16(qf[0], kf0, s);
      s = mfma16(qf[1], kf1, s);
      // exp(s/8), no max subtraction (scores bounded; division normalizes)
      #pragma unroll
      for (int j = 0; j < 4; ++j) s[j] = __expf(s[j] * 0.125f);
      sc[t] = s;
      #pragma unroll
      for (int j = 0; j < 4; ++j) plsum[j] += s[j];
    }
    #pragma unroll
    for (int c = 0; c < 4; ++c) {
      #pragma unroll
      for (int j = 0; j < 4; ++j) {
        Pw[(lk*4 + j)*40 + lr]      = f2bf(sc[2*c  ][j]);
        Pw[(lk*4 + j)*40 + 16 + lr] = f2bf(sc[2*c+1][j]);
      }
      asm volatile("s_waitcnt lgkmcnt(0)" ::: "memory");
      short8 pf = *(const short8*)&Pw[lr*40 + lk*8];
      #pragma unroll
      for (int dt = 0; dt < 4; ++dt) {
        short8 vf = *(const short8*)(VTb + (size_t)(dt*16 + lr)*S_ + kt*128 + c*32 + lk*8);
        oacc[dt] = mfma16(pf, vf, oacc[dt]);
      }
    }
    __syncthreads();
  }
  float lsum[4];
  #pragma unroll
  for (int j = 0; j < 4; ++j) {
    float s = plsum[j];
    #pragma unroll
    for (int m = 1; m < 16; m <<= 1) s += __shfl_xor(s, m);
    lsum[j] = s;
  }
  #pragma unroll
  for (int dt = 0; dt < 4; ++dt) {
    #pragma unroll
    for (int j = 0; j < 4; ++j) {
      float v = oacc[dt][j] / lsum[j];
      O[(size_t)bh*S_*D_ + (size_t)(q0 + lk*4 + j)*D_ + dt*16 + lr] = f2bf(v);
    }
  }
}

// ---------------- residual + layernorm (bf16 g input, f32 stream + bf16 copy) ----------------
template<bool PERM>
__global__ __launch_bounds__(256)
void ln_k(const unsigned short* __restrict__ g, float* __restrict__ x,
          unsigned short* __restrict__ xb,
          const float* __restrict__ gamma, const float* __restrict__ beta)
{
  int row = blockIdx.x;
  int tid = threadIdx.x;
  int e0 = tid * 4;
  ushort4v gu;
  if (PERM) {
    int b = row >> 9, s = row & 511;
    int h = e0 >> 6, d = e0 & 63;
    gu = *(const ushort4v*)&g[(((size_t)(b*H_ + h)*S_) + s)*D_ + d];
  } else {
    gu = *(const ushort4v*)&g[(size_t)row*E_ + e0];
  }
  f32x4 xv = *(const f32x4*)&x[(size_t)row*E_ + e0];
  f32x4 v;
  #pragma unroll
  for (int i = 0; i < 4; ++i) v[i] = bf2f(gu[i]) + xv[i];
  float sum = v[0]+v[1]+v[2]+v[3];
  float sq  = v[0]*v[0]+v[1]*v[1]+v[2]*v[2]+v[3]*v[3];
  #pragma unroll
  for (int m = 1; m < 64; m <<= 1) { sum += __shfl_xor(sum, m); sq += __shfl_xor(sq, m); }
  __shared__ float red[2][4];
  int lane = tid & 63, wid = tid >> 6;
  if (lane == 0) { red[0][wid] = sum; red[1][wid] = sq; }
  __syncthreads();
  float ts = red[0][0]+red[0][1]+red[0][2]+red[0][3];
  float tq = red[1][0]+red[1][1]+red[1][2]+red[1][3];
  float mu = ts * (1.0f/E_);
  float var = tq * (1.0f/E_) - mu*mu;
  float rsq = rsqrtf(var + 1e-5f);
  f32x4 y; ushort4v yb;
  #pragma unroll
  for (int i = 0; i < 4; ++i) {
    float t = (v[i]-mu)*rsq*gamma[e0+i] + beta[e0+i];
    y[i] = t; yb[i] = f2bf(t);
  }
  *(f32x4*)&x[(size_t)row*E_ + e0] = y;
  *(ushort4v*)&xb[(size_t)row*E_ + e0] = yb;
}

// ---------------- output head (all f32, exact) ----------------
__global__ __launch_bounds__(256)
void outp_k(const float* __restrict__ x, const float* __restrict__ wout,
            float* __restrict__ part)
{
  int b = blockIdx.y;
  int chunk = blockIdx.x;
  int tid = threadIdx.x;
  float acc[OUT_] = {};
  const float* xr = x + (size_t)b * S_ * E_;
  for (int j = 0; j < 32; ++j) {
    int k = chunk*8192 + j*256 + tid;
    float xv = xr[k];
    const float* wr = wout + (size_t)k * OUT_;
    #pragma unroll
    for (int o = 0; o < OUT_; ++o) acc[o] += xv * wr[o];
  }
  #pragma unroll
  for (int o = 0; o < OUT_; ++o)
    #pragma unroll
    for (int m = 1; m < 64; m <<= 1) acc[o] += __shfl_xor(acc[o], m);
  __shared__ float red[4][OUT_];
  int lane = tid & 63, wid = tid >> 6;
  if (lane == 0) {
    #pragma unroll
    for (int o = 0; o < OUT_; ++o) red[wid][o] = acc[o];
  }
  __syncthreads();
  if (tid < OUT_) {
    float s = red[0][tid] + red[1][tid] + red[2][tid] + red[3][tid];
    part[((size_t)chunk*B_ + b)*OUT_ + tid] = s;
  }
}

__global__ __launch_bounds__(192)
void outred_k(const float* __restrict__ part, const float* __restrict__ bout,
              float* __restrict__ out)
{
  int t = threadIdx.x;
  if (t < B_*OUT_) {
    int b = t / OUT_, o = t % OUT_;
    float s = 0.f;
    for (int c = 0; c < 64; ++c) s += part[((size_t)c*B_ + b)*OUT_ + o];
    s += bout[o];
    out[t] = s;
  }
}

extern "C" void kernel_launch(void* const* d_in, const int* in_sizes, int n_in,
                              void* d_out, int out_size, void* d_ws, size_t ws_size,
                              hipStream_t stream)
{
  (void)out_size;
  float* outb = (float*)d_out;

  static const int expect[14] = {8192, 16384, 1048576, 1024, 1048576, 1024,
                                 1048576, 1024, 1048576, 1024, 1024, 1024,
                                 5242880, 10};
  if (n_in != 14) { code_k<<<dim3(1), dim3(192), 0, stream>>>(outb, 9000.0f); return; }
  for (int i = 0; i < 14; ++i)
    if (in_sizes[i] != expect[i]) {
      code_k<<<dim3(1), dim3(192), 0, stream>>>(outb, 5000.0f + 100.0f*i); return;
    }

  const int* tok = (const int*)d_in[0];
  const float* emb  = (const float*)d_in[1];
  const float* wq   = (const float*)d_in[2];
  const float* bq   = (const float*)d_in[3];
  const float* wk   = (const float*)d_in[4];
  const float* bk   = (const float*)d_in[5];
  const float* wv   = (const float*)d_in[6];
  const float* bv   = (const float*)d_in[7];
  const float* wfc  = (const float*)d_in[8];
  const float* bfc  = (const float*)d_in[9];
  const float* gam  = (const float*)d_in[10];
  const float* bet  = (const float*)d_in[11];
  const float* wout = (const float*)d_in[12];
  const float* bout = (const float*)d_in[13];

  char* ws = (char*)d_ws;
  size_t off = 0;
  unsigned short* wT = (unsigned short*)(ws + off); off += (size_t)4*E_*E_*2;
  float* x  = (float*)(ws + off);                   off += (size_t)M_*E_*4;
  unsigned short* xb = (unsigned short*)(ws + off); off += (size_t)M_*E_*2;
  unsigned short* qkvb = (unsigned short*)(ws + off); off += (size_t)3*M_*E_*2;
  unsigned short* gb = (unsigned short*)(ws + off); off += (size_t)M_*E_*2;
  float* part = (float*)(ws + off);                 off += (size_t)64*B_*OUT_*4;
  if (off > ws_size) { code_k<<<dim3(1), dim3(192), 0, stream>>>(outb, 9500.0f); return; }

  transpose_k<<<dim3(16,16,4), dim3(64,4), 0, stream>>>(wq, wk, wv, wfc, wT);
  embed_k<<<dim3(M_), dim3(256), 0, stream>>>(tok, emb, x, xb);
  unsigned short* qb = qkvb;
  unsigned short* kb = qkvb + (size_t)M_*E_;
  unsigned short* vb = qkvb + (size_t)2*M_*E_;   // VT [B,H,D,S]
  for (int l = 0; l < NL_; ++l) {
    gemm_bt_k<0><<<dim3(64,16), dim3(256), 0, stream>>>(xb, wT, bq, bk, qkvb);
    gemm_bt_k<2><<<dim3(64,8),  dim3(256), 0, stream>>>(xb, wT + (size_t)2*E_*E_, bv, bv, vb);
    attn_k<<<dim3(4,256), dim3(512), 0, stream>>>(qb, kb, vb, gb);
    ln_k<true><<<dim3(M_), dim3(256), 0, stream>>>(gb, x, xb, gam, bet);
    gemm_bt_k<1><<<dim3(64,8), dim3(256), 0, stream>>>(xb, wT + (size_t)3*E_*E_, bfc, bfc, gb);
    ln_k<false><<<dim3(M_), dim3(256), 0, stream>>>(gb, x, xb, gam, bet);
  }
  outp_k<<<dim3(64,B_), dim3(256), 0, stream>>>(x, wout, part);
  outred_k<<<dim3(1), dim3(192), 0, stream>>>(part, bout, outb);
}

// Round 13
// 1222.461 us; speedup vs baseline: 1.0292x; 1.0230x over previous
//
#include <hip/hip_runtime.h>
#include <hip/hip_bf16.h>
#include <math.h>

#define B_   16
#define S_   512
#define E_   1024
#define H_   16
#define D_   64
#define NL_  6
#define OUT_ 10
#define M_   (B_*S_)

typedef short short8 __attribute__((ext_vector_type(8)));
typedef float f32x4 __attribute__((ext_vector_type(4)));
typedef int   int4v __attribute__((ext_vector_type(4)));
typedef unsigned short ushort4v __attribute__((ext_vector_type(4)));

typedef const __attribute__((address_space(1))) unsigned int* gas1_t;
typedef __attribute__((address_space(3))) unsigned int* las3_t;
#define GLD16(g,l) __builtin_amdgcn_global_load_lds((gas1_t)(g), (las3_t)(l), 16, 0, 0)

static __device__ __forceinline__ float bf2f(unsigned short u){
  union { unsigned int i; float f; } v; v.i = ((unsigned int)u) << 16; return v.f;
}
static __device__ __forceinline__ unsigned short f2bf(float f){
  union { float f; unsigned int i; } v; v.f = f;
  unsigned int r = v.i + 0x7fffu + ((v.i >> 16) & 1u);
  return (unsigned short)(r >> 16);
}
static __device__ __forceinline__ f32x4 mfma16(short8 a, short8 b, f32x4 c){
  return __builtin_amdgcn_mfma_f32_16x16x32_bf16(a, b, c, 0, 0, 0);
}

// ---------------- code writer (f32 output) ----------------
__global__ __launch_bounds__(192)
void code_k(float* __restrict__ out, float code)
{
  int t = threadIdx.x;
  if (t < B_*OUT_) out[t] = code;
}

// ---------------- weight transpose + f32->bf16: wT[n][k] = bf16(w[k][n]) ----------------
__global__ __launch_bounds__(256)
void transpose_k(const float* __restrict__ w0, const float* __restrict__ w1,
                 const float* __restrict__ w2, const float* __restrict__ w3,
                 unsigned short* __restrict__ wT)
{
  const float* w = blockIdx.z==0 ? w0 : blockIdx.z==1 ? w1 : blockIdx.z==2 ? w2 : w3;
  unsigned short* o = wT + (size_t)blockIdx.z * E_ * E_;
  __shared__ unsigned short tl[64][65];
  int n0 = blockIdx.x*64, k0 = blockIdx.y*64;
  int tx = threadIdx.x, ty = threadIdx.y;
  #pragma unroll
  for (int i = 0; i < 16; ++i)
    tl[ty + 4*i][tx] = f2bf(w[(size_t)(k0 + ty + 4*i)*E_ + n0 + tx]);
  __syncthreads();
  #pragma unroll
  for (int i = 0; i < 16; ++i)
    o[(size_t)(n0 + ty + 4*i)*E_ + k0 + tx] = tl[tx][ty + 4*i];
}

// ---------------- embedding + positional: x = 2*emb[tok] + pe[b,e] (batch-indexed, faithful) ----------------
__global__ __launch_bounds__(256)
void embed_k(const int* __restrict__ tok, const float* __restrict__ emb,
             float* __restrict__ x, unsigned short* __restrict__ xb)
{
  int row = blockIdx.x;            // b*512+s
  int b = row >> 9;
  int tk = tok[row];
  tk = tk < 0 ? 0 : (tk > 15 ? 15 : tk);
  int e0 = threadIdx.x * 4;
  const float c0 = -9.210340371976184f / (float)E_;   // -ln(10000)/E
  f32x4 ev = *(const f32x4*)&emb[(size_t)tk * E_ + e0];
  f32x4 vv; ushort4v bb;
  #pragma unroll
  for (int i = 0; i < 4; ++i) {
    int e = e0 + i;
    float dv = expf((float)(e & ~1) * c0);
    float arg = (float)b * dv;
    float pe = (e & 1) ? cosf(arg) : sinf(arg);
    float v = 2.0f * ev[i] + pe;
    vv[i] = v; bb[i] = f2bf(v);
  }
  *(f32x4*)&x[(size_t)row*E_ + e0] = vv;
  *(ushort4v*)&xb[(size_t)row*E_ + e0] = bb;
}

// ---------------- 128x128 bf16 MFMA GEMM, BT = [N][K], T2 XOR-swizzled LDS ----------------
// MODE 0: QK (grid.y=16): wsel=nyt>>3 (0=Q,1=K), writes bf16 [B,H,S,D] at outq+wsel*M*E
// MODE 2: V  (grid.y=8):  writes TRANSPOSED bf16 [B,H,D,S] at outq
// MODE 1: FC (grid.y=8):  writes bf16 [M][E] at outq
template<int MODE>
__global__ __launch_bounds__(256)
void gemm_bt_k(const unsigned short* __restrict__ A,
               const unsigned short* __restrict__ BT,
               const float* __restrict__ biasA, const float* __restrict__ biasB,
               unsigned short* __restrict__ outq)
{
  __shared__ alignas(16) unsigned short SM[(MODE==2) ? 17408 : 16384];
  unsigned short* Al = SM;
  unsigned short* Bl = SM + 8192;
  int mt = blockIdx.x;
  int nyt = blockIdx.y;
  int wsel = (MODE == 0) ? (nyt >> 3) : 0;
  int nt   = (MODE == 0) ? (nyt & 7) : nyt;
  const unsigned short* Bp = BT + (size_t)wsel * E_ * E_ + (size_t)nt * 128 * E_;
  const float* bias = (MODE == 0) ? (wsel == 0 ? biasA : biasB) : biasA;
  int tid = threadIdx.x;
  int lane = tid & 63, wid = tid >> 6;
  int wr = wid >> 1, wc = wid & 1;
  int m0 = mt * 128;
  int lr = lane & 15, lk = lane >> 4;
  int lx = lr & 7;
  int c8 = tid & 7;
  int rbase = tid >> 3;                  // r = j*32 + rbase
  int c8s = c8 ^ (rbase & 7);
  f32x4 acc[4][4] = {};
  for (int kt = 0; kt < E_/64; ++kt) {
    #pragma unroll
    for (int j = 0; j < 4; ++j) {
      int r = j*32 + rbase;
      int idx = j*256 + tid;
      GLD16(A + (size_t)(m0 + r)*E_ + kt*64 + c8s*8, &Al[idx*8]);
      GLD16(Bp + (size_t)r*E_ + kt*64 + c8s*8, &Bl[idx*8]);
    }
    __syncthreads();
    #pragma unroll
    for (int kk = 0; kk < 2; ++kk) {
      int sA = ((kk*4 + lk) ^ lx) * 8;
      short8 af[4], bfr[4];
      #pragma unroll
      for (int mi = 0; mi < 4; ++mi)
        af[mi] = *(const short8*)&Al[(wr*64 + mi*16 + lr)*64 + sA];
      #pragma unroll
      for (int ni = 0; ni < 4; ++ni)
        bfr[ni] = *(const short8*)&Bl[(wc*64 + ni*16 + lr)*64 + sA];
      #pragma unroll
      for (int mi = 0; mi < 4; ++mi)
        #pragma unroll
        for (int ni = 0; ni < 4; ++ni)
          acc[mi][ni] = mfma16(af[mi], bfr[ni], acc[mi][ni]);
    }
    __syncthreads();
  }
  if (MODE == 2) {
    unsigned short* Ct = SM;
    #pragma unroll
    for (int ni = 0; ni < 4; ++ni) {
      int nl = wc*64 + ni*16 + lr;
      float bv = bias[nt*128 + nl];
      #pragma unroll
      for (int mi = 0; mi < 4; ++mi)
        #pragma unroll
        for (int j = 0; j < 4; ++j)
          Ct[nl*136 + wr*64 + mi*16 + lk*4 + j] = f2bf(acc[mi][ni][j] + bv);
    }
    __syncthreads();
    int dl = tid >> 1, half = tid & 1;
    int h = nt*2 + (dl >> 6), d = dl & 63;
    int bb = m0 >> 9, s0 = (m0 & 511) + half*64;
    unsigned short* gp = outq + (((size_t)(bb*H_ + h)*D_ + d)*S_ + s0);
    #pragma unroll
    for (int c = 0; c < 8; ++c)
      *(int4v*)(gp + c*8) = *(const int4v*)&Ct[dl*136 + half*64 + c*8];
  } else {
    unsigned short* Cl = SM;
    #pragma unroll
    for (int ni = 0; ni < 4; ++ni) {
      int n = nt*128 + wc*64 + ni*16 + lr;
      float bv = bias[n];
      #pragma unroll
      for (int mi = 0; mi < 4; ++mi)
        #pragma unroll
        for (int j = 0; j < 4; ++j)
          Cl[(wr*64 + mi*16 + lk*4 + j)*128 + wc*64 + ni*16 + lr] =
            f2bf(acc[mi][ni][j] + bv);
    }
    __syncthreads();
    int r = tid >> 1, half = tid & 1;
    int m = m0 + r;
    unsigned short* gp;
    if (MODE == 0) {
      int bb = m >> 9, s = m & 511;
      int h = nt*2 + half;
      gp = outq + (size_t)wsel*M_*E_ + (((size_t)(bb*H_ + h)*S_ + s)*D_);
    } else {
      gp = outq + (size_t)m*E_ + nt*128 + half*64;
    }
    const unsigned short* sp = &Cl[r*128 + half*64];
    #pragma unroll
    for (int c = 0; c < 8; ++c)
      *(int4v*)(gp + c*8) = *(const int4v*)(sp + c*8);
  }
}

// ---------------- flash attention: one block per (b,h), full K in LDS ----------------
// grid 256, 512 threads (8 waves). K staged once (swizzled); V prefetched from VT[B,H,D,S];
// no-max softmax; output bf16 [B,H,S,D]. Dynamic LDS: 512*64*2 + 8*640*2 = 75776 B.
__global__ __launch_bounds__(512)
void attn_k(const unsigned short* __restrict__ Q, const unsigned short* __restrict__ K,
            const unsigned short* __restrict__ VT, unsigned short* __restrict__ O)
{
  extern __shared__ unsigned short SMEM[];
  unsigned short* Kl = SMEM;              // [512][64] chunk-swizzled
  unsigned short* Pl = SMEM + 32768;      // 8 waves x [16][40]
  int bh = blockIdx.x;
  int tid = threadIdx.x, lane = tid & 63, wid = tid >> 6;
  int lr = lane & 15, lk = lane >> 4;
  const unsigned short* Qb = Q + (size_t)bh * S_ * D_;
  const unsigned short* Kb = K + (size_t)bh * S_ * D_;
  const unsigned short* VTb = VT + (size_t)bh * S_ * D_;   // [d][s]
  unsigned short* Pw = Pl + wid * 640;
  // ---- stage all of K: 4096 x 16B chunks, source pre-swizzled ----
  #pragma unroll
  for (int j = 0; j < 8; ++j) {
    int idx = j*512 + tid;
    int r = idx >> 3, c8 = idx & 7;
    int c8s = c8 ^ (r & 7);
    GLD16(Kb + (size_t)r*D_ + c8s*8, &Kl[idx*8]);
  }
  __syncthreads();
  int sw0 = (lk     ^ (lr & 7)) * 8;      // swizzled chunk offsets for fragment reads
  int sw1 = ((4+lk) ^ (lr & 7)) * 8;
  for (int qc = 0; qc < 4; ++qc) {
    int q0 = qc*128 + wid*16;
    short8 qf0 = *(const short8*)(Qb + (size_t)(q0 + lr)*D_ + lk*8);
    short8 qf1 = *(const short8*)(Qb + (size_t)(q0 + lr)*D_ + 32 + lk*8);
    f32x4 oacc[4] = {};
    float plsum[4] = {0.f,0.f,0.f,0.f};
    for (int kt = 0; kt < 4; ++kt) {
      f32x4 sc[8];
      #pragma unroll
      for (int t = 0; t < 8; ++t) {
        const unsigned short* krow = &Kl[(kt*128 + t*16 + lr)*64];
        f32x4 s = {};
        s = mfma16(qf0, *(const short8*)(krow + sw0), s);
        s = mfma16(qf1, *(const short8*)(krow + sw1), s);
        #pragma unroll
        for (int j = 0; j < 4; ++j) s[j] = __expf(s[j] * 0.125f);
        sc[t] = s;
        #pragma unroll
        for (int j = 0; j < 4; ++j) plsum[j] += s[j];
      }
      #pragma unroll
      for (int c = 0; c < 4; ++c) {
        // prefetch V fragments BEFORE the P-LDS roundtrip (latency hides under it)
        short8 vf[4];
        #pragma unroll
        for (int dt = 0; dt < 4; ++dt)
          vf[dt] = *(const short8*)(VTb + (size_t)(dt*16 + lr)*S_ + kt*128 + c*32 + lk*8);
        #pragma unroll
        for (int j = 0; j < 4; ++j) {
          Pw[(lk*4 + j)*40 + lr]      = f2bf(sc[2*c  ][j]);
          Pw[(lk*4 + j)*40 + 16 + lr] = f2bf(sc[2*c+1][j]);
        }
        asm volatile("s_waitcnt lgkmcnt(0)" ::: "memory");
        short8 pf = *(const short8*)&Pw[lr*40 + lk*8];
        #pragma unroll
        for (int dt = 0; dt < 4; ++dt)
          oacc[dt] = mfma16(pf, vf[dt], oacc[dt]);
      }
    }
    float lsum[4];
    #pragma unroll
    for (int j = 0; j < 4; ++j) {
      float s = plsum[j];
      #pragma unroll
      for (int m = 1; m < 16; m <<= 1) s += __shfl_xor(s, m);
      lsum[j] = s;
    }
    #pragma unroll
    for (int dt = 0; dt < 4; ++dt)
      #pragma unroll
      for (int j = 0; j < 4; ++j)
        O[(size_t)bh*S_*D_ + (size_t)(q0 + lk*4 + j)*D_ + dt*16 + lr] =
          f2bf(oacc[dt][j] / lsum[j]);
  }
}

// ---------------- residual + layernorm (bf16 g input, f32 stream + bf16 copy) ----------------
template<bool PERM>
__global__ __launch_bounds__(256)
void ln_k(const unsigned short* __restrict__ g, float* __restrict__ x,
          unsigned short* __restrict__ xb,
          const float* __restrict__ gamma, const float* __restrict__ beta)
{
  int row = blockIdx.x;
  int tid = threadIdx.x;
  int e0 = tid * 4;
  ushort4v gu;
  if (PERM) {
    int b = row >> 9, s = row & 511;
    int h = e0 >> 6, d = e0 & 63;
    gu = *(const ushort4v*)&g[(((size_t)(b*H_ + h)*S_) + s)*D_ + d];
  } else {
    gu = *(const ushort4v*)&g[(size_t)row*E_ + e0];
  }
  f32x4 xv = *(const f32x4*)&x[(size_t)row*E_ + e0];
  f32x4 v;
  #pragma unroll
  for (int i = 0; i < 4; ++i) v[i] = bf2f(gu[i]) + xv[i];
  float sum = v[0]+v[1]+v[2]+v[3];
  float sq  = v[0]*v[0]+v[1]*v[1]+v[2]*v[2]+v[3]*v[3];
  #pragma unroll
  for (int m = 1; m < 64; m <<= 1) { sum += __shfl_xor(sum, m); sq += __shfl_xor(sq, m); }
  __shared__ float red[2][4];
  int lane = tid & 63, wid = tid >> 6;
  if (lane == 0) { red[0][wid] = sum; red[1][wid] = sq; }
  __syncthreads();
  float ts = red[0][0]+red[0][1]+red[0][2]+red[0][3];
  float tq = red[1][0]+red[1][1]+red[1][2]+red[1][3];
  float mu = ts * (1.0f/E_);
  float var = tq * (1.0f/E_) - mu*mu;
  float rsq = rsqrtf(var + 1e-5f);
  f32x4 y; ushort4v yb;
  #pragma unroll
  for (int i = 0; i < 4; ++i) {
    float t = (v[i]-mu)*rsq*gamma[e0+i] + beta[e0+i];
    y[i] = t; yb[i] = f2bf(t);
  }
  *(f32x4*)&x[(size_t)row*E_ + e0] = y;
  *(ushort4v*)&xb[(size_t)row*E_ + e0] = yb;
}

// ---------------- output head (all f32, exact) ----------------
__global__ __launch_bounds__(256)
void outp_k(const float* __restrict__ x, const float* __restrict__ wout,
            float* __restrict__ part)
{
  int b = blockIdx.y;
  int chunk = blockIdx.x;
  int tid = threadIdx.x;
  float acc[OUT_] = {};
  const float* xr = x + (size_t)b * S_ * E_;
  for (int j = 0; j < 32; ++j) {
    int k = chunk*8192 + j*256 + tid;
    float xv = xr[k];
    const float* wr = wout + (size_t)k * OUT_;
    #pragma unroll
    for (int o = 0; o < OUT_; ++o) acc[o] += xv * wr[o];
  }
  #pragma unroll
  for (int o = 0; o < OUT_; ++o)
    #pragma unroll
    for (int m = 1; m < 64; m <<= 1) acc[o] += __shfl_xor(acc[o], m);
  __shared__ float red[4][OUT_];
  int lane = tid & 63, wid = tid >> 6;
  if (lane == 0) {
    #pragma unroll
    for (int o = 0; o < OUT_; ++o) red[wid][o] = acc[o];
  }
  __syncthreads();
  if (tid < OUT_) {
    float s = red[0][tid] + red[1][tid] + red[2][tid] + red[3][tid];
    part[((size_t)chunk*B_ + b)*OUT_ + tid] = s;
  }
}

__global__ __launch_bounds__(192)
void outred_k(const float* __restrict__ part, const float* __restrict__ bout,
              float* __restrict__ out)
{
  int t = threadIdx.x;
  if (t < B_*OUT_) {
    int b = t / OUT_, o = t % OUT_;
    float s = 0.f;
    for (int c = 0; c < 64; ++c) s += part[((size_t)c*B_ + b)*OUT_ + o];
    s += bout[o];
    out[t] = s;
  }
}

extern "C" void kernel_launch(void* const* d_in, const int* in_sizes, int n_in,
                              void* d_out, int out_size, void* d_ws, size_t ws_size,
                              hipStream_t stream)
{
  (void)out_size;
  float* outb = (float*)d_out;

  static const int expect[14] = {8192, 16384, 1048576, 1024, 1048576, 1024,
                                 1048576, 1024, 1048576, 1024, 1024, 1024,
                                 5242880, 10};
  if (n_in != 14) { code_k<<<dim3(1), dim3(192), 0, stream>>>(outb, 9000.0f); return; }
  for (int i = 0; i < 14; ++i)
    if (in_sizes[i] != expect[i]) {
      code_k<<<dim3(1), dim3(192), 0, stream>>>(outb, 5000.0f + 100.0f*i); return;
    }

  const int* tok = (const int*)d_in[0];
  const float* emb  = (const float*)d_in[1];
  const float* wq   = (const float*)d_in[2];
  const float* bq   = (const float*)d_in[3];
  const float* wk   = (const float*)d_in[4];
  const float* bk   = (const float*)d_in[5];
  const float* wv   = (const float*)d_in[6];
  const float* bv   = (const float*)d_in[7];
  const float* wfc  = (const float*)d_in[8];
  const float* bfc  = (const float*)d_in[9];
  const float* gam  = (const float*)d_in[10];
  const float* bet  = (const float*)d_in[11];
  const float* wout = (const float*)d_in[12];
  const float* bout = (const float*)d_in[13];

  char* ws = (char*)d_ws;
  size_t off = 0;
  unsigned short* wT = (unsigned short*)(ws + off); off += (size_t)4*E_*E_*2;
  float* x  = (float*)(ws + off);                   off += (size_t)M_*E_*4;
  unsigned short* xb = (unsigned short*)(ws + off); off += (size_t)M_*E_*2;
  unsigned short* qkvb = (unsigned short*)(ws + off); off += (size_t)3*M_*E_*2;
  unsigned short* gb = (unsigned short*)(ws + off); off += (size_t)M_*E_*2;
  float* part = (float*)(ws + off);                 off += (size_t)64*B_*OUT_*4;
  if (off > ws_size) { code_k<<<dim3(1), dim3(192), 0, stream>>>(outb, 9500.0f); return; }

  transpose_k<<<dim3(16,16,4), dim3(64,4), 0, stream>>>(wq, wk, wv, wfc, wT);
  embed_k<<<dim3(M_), dim3(256), 0, stream>>>(tok, emb, x, xb);
  unsigned short* qb = qkvb;
  unsigned short* kb = qkvb + (size_t)M_*E_;
  unsigned short* vb = qkvb + (size_t)2*M_*E_;   // VT [B,H,D,S]
  for (int l = 0; l < NL_; ++l) {
    gemm_bt_k<0><<<dim3(64,16), dim3(256), 0, stream>>>(xb, wT, bq, bk, qkvb);
    gemm_bt_k<2><<<dim3(64,8),  dim3(256), 0, stream>>>(xb, wT + (size_t)2*E_*E_, bv, bv, vb);
    attn_k<<<dim3(256), dim3(512), 75776, stream>>>(qb, kb, vb, gb);
    ln_k<true><<<dim3(M_), dim3(256), 0, stream>>>(gb, x, xb, gam, bet);
    gemm_bt_k<1><<<dim3(64,8), dim3(256), 0, stream>>>(xb, wT + (size_t)3*E_*E_, bfc, bfc, gb);
    ln_k<false><<<dim3(M_), dim3(256), 0, stream>>>(gb, x, xb, gam, bet);
  }
  outp_k<<<dim3(64,B_), dim3(256), 0, stream>>>(x, wout, part);
  outred_k<<<dim3(1), dim3(192), 0, stream>>>(part, bout, outb);
}